// Round 11
// baseline (147.971 us; speedup 1.0000x reference)
//
#include <hip/hip_runtime.h>
#include <cstdint>

#define HH 3000
#define WW 3000
#define WPR 48                    // 64-bit words per row (3000 bits, padded; word 46 partial, 47 zero)
#define NW (HH * WPR)             // 144,000

typedef unsigned long long u64;
typedef float f4v __attribute__((ext_vector_type(4)));

// ws layout (every byte written before read):
//   +0        u64 bits[NW]        1,152,000 B
//   +1152000  int rowSums[3000]
//   +1164032  int P[NW]           576,000 B
#define BITS_OFF 0
#define ROWS_OFF 1152000
#define P_OFF    1164032

__device__ __forceinline__ void nt_store4(float a, float b, float c, float d, float4* p) {
    f4v x; x.x = a; x.y = b; x.z = c; x.w = d;
    __builtin_nontemporal_store(x, (f4v*)p);
}

// Inline layout detection from the first 256 words (1 KB, L2-broadcast):
// int32 bools -> words in {0,1}; byte bools -> words in [0,0x01010101];
// float bools -> words in {0,0x3F800000}.
__device__ __forceinline__ int detect_mode(const void* acts, int t, int lane, int wv,
                                           int* s_red, int* s_mode) {
    int v = (int)((const unsigned*)acts)[t];
    #pragma unroll
    for (int off = 32; off > 0; off >>= 1) v = max(v, __shfl_down(v, off));
    if (lane == 0) s_red[wv] = v;
    __syncthreads();
    if (t == 0) {
        int mx = max(max(s_red[0], s_red[1]), max(s_red[2], s_red[3]));
        *s_mode = (mx > 1 && mx <= 0x01010101) ? 1 : 0;
    }
    __syncthreads();
    return *s_mode;
}

// ---- build: one block per row; vectorized loads (8 cells/thread/iter),
//      8-lane shfl-or combine into 64-bit words ----
__global__ __launch_bounds__(256) void k_build(const void* __restrict__ acts,
                                               u64* __restrict__ bits,
                                               int* __restrict__ rowSums) {
    __shared__ int s_red[4];
    __shared__ int s_mode;
    const int t = threadIdx.x, lane = t & 63, wv = t >> 6;
    const int mode = detect_mode(acts, t, lane, wv, s_red, &s_mode);

    const int r = blockIdx.x;
    int rcnt = 0;
    #pragma unroll
    for (int it = 0; it < 2; ++it) {
        const int c0 = it * 2048 + t * 8;       // first of 8 cells this thread covers
        u64 m8 = 0;
        if (c0 < WW) {                          // c0 multiple of 8, so c0+7 <= WW-1
            if (mode) {
                u64 x = *(const u64*)((const unsigned char*)acts + (long)r * WW + c0);
                u64 y = x | (x >> 4); y |= y >> 2; y |= y >> 1;
                y &= 0x0101010101010101ull;                 // LSB of each nonzero byte
                m8 = (y * 0x0102040810204080ull) >> 56;     // pack byte-LSBs -> 8 bits
            } else {
                const unsigned* p = (const unsigned*)acts + (long)r * WW + c0;
                uint4 a  = *(const uint4*)p;
                uint4 b4 = *(const uint4*)(p + 4);
                m8 = (u64)(a.x  != 0u)        | ((u64)(a.y  != 0u) << 1) |
                     ((u64)(a.z  != 0u) << 2) | ((u64)(a.w  != 0u) << 3) |
                     ((u64)(b4.x != 0u) << 4) | ((u64)(b4.y != 0u) << 5) |
                     ((u64)(b4.z != 0u) << 6) | ((u64)(b4.w != 0u) << 7);
            }
        }
        rcnt += __popcll(m8);
        u64 word = m8 << (8 * (lane & 7));
        word |= __shfl_xor(word, 1);
        word |= __shfl_xor(word, 2);
        word |= __shfl_xor(word, 4);            // all 8 lanes of group hold the word
        const int wi = it * 32 + (t >> 3);      // word index within row
        if ((t & 7) == 0 && wi < WPR) bits[r * WPR + wi] = word;
    }
    #pragma unroll
    for (int off = 32; off > 0; off >>= 1) rcnt += __shfl_down(rcnt, off);
    if (lane == 0) s_red[wv] = rcnt;
    __syncthreads();
    if (t == 0) rowSums[r] = s_red[0] + s_red[1] + s_red[2] + s_red[3];
}

// ---- prefix: 4 rows per block; redundant base reduction + wave scan per row ----
__global__ __launch_bounds__(256) void k_prefixP(const u64* __restrict__ bits,
                                                 const int* __restrict__ rowSums,
                                                 int* __restrict__ P) {
    __shared__ int s_red[4];
    const int t = threadIdx.x, lane = t & 63, wv = t >> 6;
    const int r0 = blockIdx.x * 4;
    int s = 0;
    for (int idx = t; idx < r0; idx += 256) s += rowSums[idx];
    #pragma unroll
    for (int off = 32; off > 0; off >>= 1) s += __shfl_down(s, off);
    if (lane == 0) s_red[wv] = s;
    __syncthreads();
    int base = s_red[0] + s_red[1] + s_red[2] + s_red[3];

    const int r = r0 + wv;
    if (r < HH) {
        int rbase = base;
        if (wv >= 1) rbase += rowSums[r0];
        if (wv >= 2) rbase += rowSums[r0 + 1];
        if (wv >= 3) rbase += rowSums[r0 + 2];
        const int w = r * WPR + lane;
        int v = (lane < WPR) ? __popcll(bits[w]) : 0;
        int x = v;
        #pragma unroll
        for (int off = 1; off < 64; off <<= 1) {
            int y = __shfl_up(x, off);
            if (lane >= off) x += y;
        }
        if (lane < WPR) P[w] = rbase + (x - v);  // absolute exclusive prefix
    }
}

// ---- emit: grid (6, 3000); 2 words/wave; load-all -> compute-all -> store-all.
// All loads unconditional with clamped in-bounds addresses (predicates on values only);
// bits/P lookups are wave-uniform -> forced scalar via readfirstlane.
// bit == lane by construction; padding words are zero.
__global__ __launch_bounds__(256) void k_emit(const u64* __restrict__ bits,
                                              const int* __restrict__ P,
                                              const float* __restrict__ wts,
                                              float* __restrict__ out, int N) {
    const int t = threadIdx.x;
    const int lane = t & 63;
    const int wv = t >> 6;
    const int i = blockIdx.y;

    float4* valsg = (float4*)out;                     // N float4s
    float4* indsg = (float4*)(out + (size_t)N * 4);   // 2N float4s

    const int id = (i < HH - 1) ? i + 1 : i;          // clamped down row
    const int iu = (i > 0) ? i - 1 : 0;               // clamped up row
    const bool okd_i = (i < HH - 1), oku_i = (i > 0);

    // ---------- load phase: everything independent, issued before any use ----------
    int  jj[2];
    u64  ms_[2], md_[2], mu_[2], mr_[2], ml_[2];
    int  Pw_[2], Pd_[2], Pu_[2], Pr_[2], Pl_[2];
    float wdn_[2], wup_[2], wrt_[2], wlf_[2];

    #pragma unroll
    for (int h = 0; h < 2; ++h) {
        const int wi = blockIdx.x * 8 + h * 4 + wv;   // 0..47
        const int j  = wi * 64 + lane;
        jj[h] = j;
        const int jc = (j < WW) ? j : (WW - 1);

        const int w  = __builtin_amdgcn_readfirstlane(i  * WPR + wi);
        const int wd = __builtin_amdgcn_readfirstlane(id * WPR + wi);
        const int wu = __builtin_amdgcn_readfirstlane(iu * WPR + wi);
        const int wr = (w + 1 < NW) ? w + 1 : w;
        const int wl = (w > 0) ? w - 1 : w;

        ms_[h] = bits[w];  md_[h] = bits[wd];  mu_[h] = bits[wu];
        mr_[h] = bits[wr]; ml_[h] = bits[wl];
        Pw_[h] = P[w];  Pd_[h] = P[wd];  Pu_[h] = P[wu];
        Pr_[h] = P[wr]; Pl_[h] = P[wl];

        wdn_[h] = wts[(long)id * WW + jc];
        wup_[h] = wts[(long)iu * WW + jc];
        wrt_[h] = wts[(long)i * WW + ((jc < WW - 1) ? jc + 1 : jc)];
        wlf_[h] = wts[(long)i * WW + ((jc > 0) ? jc - 1 : 0)];
    }

    // ---------- compute + store phase ----------
    #pragma unroll
    for (int h = 0; h < 2; ++h) {
        const int j = jj[h];
        const u64 mself = ms_[h];
        const bool act = (mself >> lane) & 1ull;
        const u64 below = (1ull << lane) - 1ull;
        const int v = Pw_[h] + __popcll(mself & below);
        const float nf = (float)v;

        // (1,0) down
        bool a0 = okd_i && ((md_[h] >> lane) & 1ull);
        float val0 = a0 ? wdn_[h] : 0.f, sf0 = a0 ? nf : 0.f;
        float tf0 = a0 ? (float)(Pd_[h] + __popcll(md_[h] & below)) : 0.f;
        // (-1,0) up
        bool a1 = oku_i && ((mu_[h] >> lane) & 1ull);
        float val1 = a1 ? wup_[h] : 0.f, sf1 = a1 ? nf : 0.f;
        float tf1 = a1 ? (float)(Pu_[h] + __popcll(mu_[h] & below)) : 0.f;
        // (0,1) right — cross-word only at lane 63
        bool okr = (j < WW - 1);
        u64 wdr = (lane < 63) ? mself : mr_[h];
        int br  = (lane < 63) ? lane + 1 : 0;
        int Pbr = (lane < 63) ? Pw_[h] : Pr_[h];
        bool a2 = okr && ((wdr >> br) & 1ull);
        float val2 = a2 ? wrt_[h] : 0.f, sf2 = a2 ? nf : 0.f;
        float tf2 = a2 ? (float)(Pbr + __popcll(wdr & ((1ull << br) - 1ull))) : 0.f;
        // (0,-1) left — cross-word only at lane 0
        bool okl = (j > 0);
        u64 wdl = (lane > 0) ? mself : ml_[h];
        int bl  = (lane > 0) ? lane - 1 : 63;
        int Pbl = (lane > 0) ? Pw_[h] : Pl_[h];
        bool a3 = okl && ((wdl >> bl) & 1ull);
        float val3 = a3 ? wlf_[h] : 0.f, sf3 = a3 ? nf : 0.f;
        float tf3 = a3 ? (float)(Pbl + __popcll(wdl & ((1ull << bl) - 1ull))) : 0.f;

        if (act) {
            nt_store4(val0, val1, val2, val3, &valsg[v]);
            nt_store4(sf0, tf0, sf1, tf1, &indsg[2 * (size_t)v]);
            nt_store4(sf2, tf2, sf3, tf3, &indsg[2 * (size_t)v + 1]);
        }
    }
}

extern "C" void kernel_launch(void* const* d_in, const int* in_sizes, int n_in,
                              void* d_out, int out_size, void* d_ws, size_t ws_size,
                              hipStream_t stream) {
    const void* acts = d_in[0];
    const float* wts = (const float*)d_in[1];
    float* out = (float*)d_out;
    const int N = out_size / 12;

    u64* bits = (u64*)((char*)d_ws + BITS_OFF);
    int* rows = (int*)((char*)d_ws + ROWS_OFF);
    int* P    = (int*)((char*)d_ws + P_OFF);

    k_build<<<HH, 256, 0, stream>>>(acts, bits, rows);
    k_prefixP<<<(HH + 3) / 4, 256, 0, stream>>>(bits, rows, P);
    k_emit<<<dim3(6, HH), 256, 0, stream>>>(bits, P, wts, out, N);
}

// Round 12
// 103.608 us; speedup vs baseline: 1.4282x; 1.4282x over previous
//
#include <hip/hip_runtime.h>
#include <cstdint>

#define HH 3000
#define WW 3000
#define WPR 48                    // 64-bit words per row (3000 bits, padded; word 46 partial, 47 zero)
#define NW (HH * WPR)             // 144,000

typedef unsigned long long u64;
typedef float f4v __attribute__((ext_vector_type(4)));

// ws layout (every byte written before read):
//   +0        u64 bits[NW]        1,152,000 B
//   +1152000  int rowSums[3000]
//   +1164032  int P[NW]           576,000 B
#define BITS_OFF 0
#define ROWS_OFF 1152000
#define P_OFF    1164032

__device__ __forceinline__ void nt_store4(float a, float b, float c, float d, float4* p) {
    f4v x; x.x = a; x.y = b; x.z = c; x.w = d;
    __builtin_nontemporal_store(x, (f4v*)p);
}

// Inline layout detection from the first 256 words (1 KB, L2-broadcast):
// int32 bools -> words in {0,1}; byte bools -> words in [0,0x01010101];
// float bools -> words in {0,0x3F800000}.
__device__ __forceinline__ int detect_mode(const void* acts, int t, int lane, int wv,
                                           int* s_red, int* s_mode) {
    int v = (int)((const unsigned*)acts)[t];
    #pragma unroll
    for (int off = 32; off > 0; off >>= 1) v = max(v, __shfl_down(v, off));
    if (lane == 0) s_red[wv] = v;
    __syncthreads();
    if (t == 0) {
        int mx = max(max(s_red[0], s_red[1]), max(s_red[2], s_red[3]));
        *s_mode = (mx > 1 && mx <= 0x01010101) ? 1 : 0;
    }
    __syncthreads();
    return *s_mode;
}

// ---- build: one block per row; vectorized loads (8 cells/thread/iter),
//      8-lane shfl-or combine into 64-bit words ----
__global__ __launch_bounds__(256) void k_build(const void* __restrict__ acts,
                                               u64* __restrict__ bits,
                                               int* __restrict__ rowSums) {
    __shared__ int s_red[4];
    __shared__ int s_mode;
    const int t = threadIdx.x, lane = t & 63, wv = t >> 6;
    const int mode = detect_mode(acts, t, lane, wv, s_red, &s_mode);

    const int r = blockIdx.x;
    int rcnt = 0;
    #pragma unroll
    for (int it = 0; it < 2; ++it) {
        const int c0 = it * 2048 + t * 8;       // first of 8 cells this thread covers
        u64 m8 = 0;
        if (c0 < WW) {                          // c0 multiple of 8, so c0+7 <= WW-1
            if (mode) {
                u64 x = *(const u64*)((const unsigned char*)acts + (long)r * WW + c0);
                u64 y = x | (x >> 4); y |= y >> 2; y |= y >> 1;
                y &= 0x0101010101010101ull;                 // LSB of each nonzero byte
                m8 = (y * 0x0102040810204080ull) >> 56;     // pack byte-LSBs -> 8 bits
            } else {
                const unsigned* p = (const unsigned*)acts + (long)r * WW + c0;
                uint4 a  = *(const uint4*)p;
                uint4 b4 = *(const uint4*)(p + 4);
                m8 = (u64)(a.x  != 0u)        | ((u64)(a.y  != 0u) << 1) |
                     ((u64)(a.z  != 0u) << 2) | ((u64)(a.w  != 0u) << 3) |
                     ((u64)(b4.x != 0u) << 4) | ((u64)(b4.y != 0u) << 5) |
                     ((u64)(b4.z != 0u) << 6) | ((u64)(b4.w != 0u) << 7);
            }
        }
        rcnt += __popcll(m8);
        u64 word = m8 << (8 * (lane & 7));
        word |= __shfl_xor(word, 1);
        word |= __shfl_xor(word, 2);
        word |= __shfl_xor(word, 4);            // all 8 lanes of group hold the word
        const int wi = it * 32 + (t >> 3);      // word index within row
        if ((t & 7) == 0 && wi < WPR) bits[r * WPR + wi] = word;
    }
    #pragma unroll
    for (int off = 32; off > 0; off >>= 1) rcnt += __shfl_down(rcnt, off);
    if (lane == 0) s_red[wv] = rcnt;
    __syncthreads();
    if (t == 0) rowSums[r] = s_red[0] + s_red[1] + s_red[2] + s_red[3];
}

// ---- prefix: 4 rows per block; redundant base reduction + wave scan per row ----
__global__ __launch_bounds__(256) void k_prefixP(const u64* __restrict__ bits,
                                                 const int* __restrict__ rowSums,
                                                 int* __restrict__ P) {
    __shared__ int s_red[4];
    const int t = threadIdx.x, lane = t & 63, wv = t >> 6;
    const int r0 = blockIdx.x * 4;
    int s = 0;
    for (int idx = t; idx < r0; idx += 256) s += rowSums[idx];
    #pragma unroll
    for (int off = 32; off > 0; off >>= 1) s += __shfl_down(s, off);
    if (lane == 0) s_red[wv] = s;
    __syncthreads();
    int base = s_red[0] + s_red[1] + s_red[2] + s_red[3];

    const int r = r0 + wv;
    if (r < HH) {
        int rbase = base;
        if (wv >= 1) rbase += rowSums[r0];
        if (wv >= 2) rbase += rowSums[r0 + 1];
        if (wv >= 3) rbase += rowSums[r0 + 2];
        const int w = r * WPR + lane;
        int v = (lane < WPR) ? __popcll(bits[w]) : 0;
        int x = v;
        #pragma unroll
        for (int off = 1; off < 64; off <<= 1) {
            int y = __shfl_up(x, off);
            if (lane >= off) x += y;
        }
        if (lane < WPR) P[w] = rbase + (x - v);  // absolute exclusive prefix
    }
}

// ---- emit: grid (6, 3000), natural block order; 2 words/wave;
//      direct per-lane nt stores, no LDS (R8 best-verified form) ----
// bit == lane by construction; padding words are zero so no row-end bounds checks needed.
__global__ __launch_bounds__(256) void k_emit(const u64* __restrict__ bits,
                                              const int* __restrict__ P,
                                              const float* __restrict__ wts,
                                              float* __restrict__ out, int N) {
    const int t = threadIdx.x;
    const int lane = t & 63;
    const int wv = t >> 6;
    const int i = blockIdx.y;

    float4* valsg = (float4*)out;                     // N float4s
    float4* indsg = (float4*)(out + (size_t)N * 4);   // 2N float4s

    #pragma unroll
    for (int half = 0; half < 2; ++half) {
        const int wi = blockIdx.x * 8 + half * 4 + wv;   // word index in row, 0..47
        const int j = wi * 64 + lane;
        const int w = i * WPR + wi;
        const u64 mself = bits[w];
        if (!((mself >> lane) & 1ull)) continue;         // covers j >= WW too (padding bits 0)

        const int v = P[w] + __popcll(mself & ((1ull << lane) - 1ull));
        const float nf = (float)v;
        const long c = (long)i * WW + j;

        float val0, val1, val2, val3, sf0, sf1, sf2, sf3, tf0, tf1, tf2, tf3;
        { // (1,0) down
            bool ok = (i < HH - 1);
            u64 wd = ok ? bits[w + WPR] : 0ull;
            bool aa = ok && ((wd >> lane) & 1ull);
            val0 = aa ? wts[c + WW] : 0.f; sf0 = aa ? nf : 0.f;
            tf0 = aa ? (float)(P[w + WPR] + __popcll(wd & ((1ull << lane) - 1ull))) : 0.f;
        }
        { // (-1,0) up
            bool ok = (i > 0);
            u64 wd = ok ? bits[w - WPR] : 0ull;
            bool aa = ok && ((wd >> lane) & 1ull);
            val1 = aa ? wts[c - WW] : 0.f; sf1 = aa ? nf : 0.f;
            tf1 = aa ? (float)(P[w - WPR] + __popcll(wd & ((1ull << lane) - 1ull))) : 0.f;
        }
        { // (0,1) right — cross-word only at lane 63
            bool ok = (j < WW - 1);
            int wn = (lane < 63) ? w : w + 1;
            int b2 = (lane < 63) ? lane + 1 : 0;
            u64 wd = ok ? ((lane < 63) ? mself : bits[wn]) : 0ull;
            bool aa = ok && ((wd >> b2) & 1ull);
            val2 = aa ? wts[c + 1] : 0.f; sf2 = aa ? nf : 0.f;
            tf2 = aa ? (float)(P[wn] + __popcll(wd & ((1ull << b2) - 1ull))) : 0.f;
        }
        { // (0,-1) left
            bool ok = (j > 0);
            int wn = (lane > 0) ? w : w - 1;
            int b2 = (lane > 0) ? lane - 1 : 63;
            u64 wd = ok ? ((lane > 0) ? mself : bits[wn]) : 0ull;
            bool aa = ok && ((wd >> b2) & 1ull);
            val3 = aa ? wts[c - 1] : 0.f; sf3 = aa ? nf : 0.f;
            tf3 = aa ? (float)(P[wn] + __popcll(wd & ((1ull << b2) - 1ull))) : 0.f;
        }

        nt_store4(val0, val1, val2, val3, &valsg[v]);
        nt_store4(sf0, tf0, sf1, tf1, &indsg[2 * (size_t)v]);
        nt_store4(sf2, tf2, sf3, tf3, &indsg[2 * (size_t)v + 1]);
    }
}

extern "C" void kernel_launch(void* const* d_in, const int* in_sizes, int n_in,
                              void* d_out, int out_size, void* d_ws, size_t ws_size,
                              hipStream_t stream) {
    const void* acts = d_in[0];
    const float* wts = (const float*)d_in[1];
    float* out = (float*)d_out;
    const int N = out_size / 12;

    u64* bits = (u64*)((char*)d_ws + BITS_OFF);
    int* rows = (int*)((char*)d_ws + ROWS_OFF);
    int* P    = (int*)((char*)d_ws + P_OFF);

    k_build<<<HH, 256, 0, stream>>>(acts, bits, rows);
    k_prefixP<<<(HH + 3) / 4, 256, 0, stream>>>(bits, rows, P);
    k_emit<<<dim3(6, HH), 256, 0, stream>>>(bits, P, wts, out, N);
}